// Round 4
// baseline (2005.913 us; speedup 1.0000x reference)
//
#include <hip/hip_runtime.h>
#include <math.h>

typedef unsigned long long u64;
typedef unsigned int u32;

// Problem constants
#define L 512
#define E 300
#define H 512          // per-direction hidden
#define G4H 2048       // 4*H
#define NTAGS 20
#define START_TAG 18
#define STOP_TAG 19

#define KC 100         // k1 K-chunk (300 = 3*100)

// Workspace layout (bytes) -- footprint UNCHANGED from the verified baseline
#define OFF_XW    0u          // f32 [2][512][2048] (permuted cols) = 8388608
#define OFF_HIST  8388608u    // f32 [2][512][512]  = 2097152
#define OFF_HBUF  10485760u   // u64 [2][2][512] canonical h slots = 16384
#define OFF_FEATS 10502144u   // f32 [512][20] = 40960. DEAD until k3 ->
                              // reused during k2 as:
                              //   +0     : mirror u64 [2][2][512] = 16384 B
                              //   +16384 : cntX  int[8]  (per-XCD tickets)
                              //   +16416 : claimed int[64] (slot bitmap)

// ---------------------------------------------------------------------------
// K0: zero mirror + control block (must run before every k2 replay; k3
// overwrites this region with feats afterwards, so tags would be garbage).
__global__ void k0_init(u64* __restrict__ z) {
    int t = threadIdx.x;
#pragma unroll
    for (int i = 0; i < 9; ++i) {
        int idx = t * 9 + i;            // 256*9 = 2304 u64 = 18432 B
        if (idx < 2304) z[idx] = 0;
    }
}

// ---------------------------------------------------------------------------
// K1: tiled GEMM  xw[dir][t][pos(n)] = embed[sent[t]] . wih[n] + bias(n).
// (unchanged from verified baseline)
__global__ __launch_bounds__(256) void k1_xw(
    const int* __restrict__ sentence, const float* __restrict__ embed,
    const float* __restrict__ wih_f, const float* __restrict__ wih_b,
    const float* __restrict__ bih_f, const float* __restrict__ bhh_f,
    const float* __restrict__ bih_b, const float* __restrict__ bhh_b,
    float* __restrict__ xw) {
    __shared__ float wST[KC][68];   // [k][n]
    __shared__ float xST[KC][68];   // [k][t]
    __shared__ int   sT[64];

    const int tid = threadIdx.x;
    const int tx = tid & 15;        // t micro index
    const int ty = tid >> 4;        // n micro index
    const int n_base = blockIdx.x * 64;
    const int t_base = blockIdx.y * 64;
    const int dir = blockIdx.z;
    const float* wih = dir ? wih_b : wih_f;
    const float* bih = dir ? bih_b : bih_f;
    const float* bhh = dir ? bhh_b : bhh_f;

    if (tid < 64) sT[tid] = sentence[t_base + tid];
    __syncthreads();

    float acc[4][4];
#pragma unroll
    for (int i = 0; i < 4; ++i)
#pragma unroll
        for (int j = 0; j < 4; ++j) acc[i][j] = 0.f;

    for (int kc = 0; kc < E; kc += KC) {
#pragma unroll
        for (int i = 0; i < 25; ++i) {
            int idx = i * 256 + tid;          // < 6400
            int row = idx / KC, col = idx % KC;
            wST[col][row] = wih[(size_t)(n_base + row) * E + kc + col];
        }
#pragma unroll
        for (int i = 0; i < 25; ++i) {
            int idx = i * 256 + tid;
            int trow = idx / KC, col = idx % KC;
            xST[col][trow] = embed[(size_t)sT[trow] * E + kc + col];
        }
        __syncthreads();

#pragma unroll 4
        for (int k = 0; k < KC; ++k) {
            float4 wv4 = *(const float4*)&wST[k][ty * 4];
            float4 xv4 = *(const float4*)&xST[k][tx * 4];
            float wv[4] = {wv4.x, wv4.y, wv4.z, wv4.w};
            float xv[4] = {xv4.x, xv4.y, xv4.z, xv4.w};
#pragma unroll
            for (int i = 0; i < 4; ++i)
#pragma unroll
                for (int j = 0; j < 4; ++j)
                    acc[i][j] = fmaf(wv[i], xv[j], acc[i][j]);
        }
        __syncthreads();
    }

#pragma unroll
    for (int i = 0; i < 4; ++i) {
        int n = n_base + ty * 4 + i;
        float b = bih[n] + bhh[n];
        int u = n & (H - 1), g = n >> 9;
        int pos = (u >> 4) * 64 + g * 16 + (u & 15);   // gate-major in block
#pragma unroll
        for (int j = 0; j < 4; ++j) {
            int t = t_base + tx * 4 + j;
            xw[((size_t)(dir * L) + t) * G4H + pos] = acc[i][j] + b;
        }
    }
}

// ---------------------------------------------------------------------------
// K2: bidirectional LSTM recurrence, XCD-clustered.
//
// r3 post-mortem: clustering worked (FETCH 25.7->12.0 GB: polls moved to
// the XCD-local L2) but the poll loop ran a canonical agent-scope check
// (with implicit s_waitcnt vmcnt(0)!) EVERY iteration, draining the mirror
// pipeline -> sampling period ~1400cy, worse than baseline. This round:
// pure 3-deep pipelined sc0 mirror poll (hand-counted vmcnt(2) rotation,
// sampling ~L2RT/3); canonical backstop only once per 8 full misses (never
// taken when clustering holds; exists so misplacement degrades instead of
// hanging).
//
// Placement (verified r3): 86.4KB LDS -> 1 WG/CU; grid=256=CU count ->
// 32 WGs/XCD. Per-XCD ticket: XCD0 ranks 0..31 CAS-claim fwd slots, XCD1
// bwd. All other WGs are spares: sleep ~30us, adopt any unclaimed slot
// (idempotent duplicates are safe), else exit. No deadlock possible.
#define SHM_U64 10800   // 86400 B LDS: 2 WGs/CU impossible (172800 > 160K)

__global__ __launch_bounds__(512, 1) void k2_lstm(
    const float* __restrict__ whh_f, const float* __restrict__ whh_b,
    const float* __restrict__ h0, const float* __restrict__ c0,
    const float* __restrict__ xw, float* __restrict__ hist,
    u64* __restrict__ hbuf, u64* __restrict__ mir,
    int* __restrict__ cntX, int* __restrict__ claimed) {

    __shared__ u64 shm[SHM_U64];
    float* pbuf = (float*)(shm + 8);           // [2][8][68] floats = 4352 B
#define PB(p, w, l) pbuf[(((p) * 8 + (w)) * 68) + (l)]
    __shared__ int slot_sh;

    const int tid = threadIdx.x;

    // --- slot assignment: primary claim, spare adoption (verified r3) ---
    if (tid == 0) {
        shm[SHM_U64 - 1] = 0;                  // keep LDS tail alive
        u32 xcd = __builtin_amdgcn_s_getreg(14356) & 7;  // hwreg(20,0,8)
        int r = atomicAdd(&cntX[xcd], 1);      // device-scope ticket
        int slot = -1;
        if (xcd <= 1 && r < 32) {
            int cand = (int)xcd * 32 + r;      // XCD0->fwd 0..31, XCD1->bwd
            if (atomicCAS(&claimed[cand], 0, 1) == 0) slot = cand;
        }
        slot_sh = slot;
    }
    __syncthreads();
    int slot = slot_sh;

    if (slot < 0) {
        // spare: give primaries ~30us to register, then adopt stragglers
        if (tid == 0) {
            for (int i = 0; i < 8; ++i) __builtin_amdgcn_s_sleep(127);
            int got = -1;
            for (int sl = 0; sl < 64 && got < 0; ++sl)
                if (atomicCAS(&claimed[sl], 0, 1) == 0) got = sl;
            slot_sh = got;
        }
        __syncthreads();
        slot = slot_sh;
        if (slot < 0) return;                  // all slots covered -> exit
    }

    const int dir = slot >> 5;
    const int wg  = slot & 31;
    const int wv  = tid >> 6;       // wave id = dot k-slice
    const int l   = tid & 63;
    const int g   = l >> 4;         // gate: 0=i 1=f 2=g 3=o
    const int j   = l & 15;         // unit within WG
    const int grow = g * H + wg * 16 + j;

    const float* whh = dir ? whh_b : whh_f;
    float* histd = hist + (size_t)dir * L * H;
    u64* hb   = hbuf + dir * 1024;  // canonical [parity][512]
    u64* mird = mir  + dir * 1024;  // mirror    [parity][512]

    // this lane's 64 Whh weights (row grow, slice wv) -> regs
    float w[64];
    {
        const float* wp = whh + (size_t)grow * H + wv * 64;
#pragma unroll
        for (int i = 0; i < 64; i += 4) {
            float4 v = *(const float4*)(wp + i);
            w[i] = v.x; w[i+1] = v.y; w[i+2] = v.z; w[i+3] = v.w;
        }
    }

    // c state lives on wave0 lanes 0..15 (unit = wg*16 + tid)
    float c = (tid < 16) ? c0[dir * H + wg * 16 + tid] : 0.f;

    for (int s = 1; s <= L; ++s) {
        const int t = dir ? (L - s) : (s - 1);
        const int par = s & 1;

        // ---- acquire h_{s-1}[tid]: 3-deep pipelined sc0 mirror poll ----
        float hval;
        if (s == 1) {
            hval = h0[dir * H + tid];
        } else {
            const u32 want = (u32)(s - 1);
            const u64* mslot = mird + ((s - 1) & 1) * 512 + tid;
            u64* cslot = hb + ((s - 1) & 1) * 512 + tid;
            u64 v0, v1, v2, got;
            asm volatile("global_load_dwordx2 %0, %3, off sc0\n\t"
                         "global_load_dwordx2 %1, %3, off sc0\n\t"
                         "global_load_dwordx2 %2, %3, off sc0"
                         : "=&v"(v0), "=&v"(v1), "=&v"(v2)
                         : "v"(mslot) : "memory");
            int miss = 0;
            while (true) {
                // in-order vmcnt decrement: vmcnt(2) waits for the oldest
                // poll load (and any earlier stores) only.
                asm volatile("s_waitcnt vmcnt(2)" : "+v"(v0) :: "memory");
                __builtin_amdgcn_sched_barrier(0);
                if ((u32)(v0 >> 32) == want) { got = v0; break; }
                asm volatile("global_load_dwordx2 %0, %1, off sc0"
                             : "=&v"(v0) : "v"(mslot) : "memory");
                asm volatile("s_waitcnt vmcnt(2)" : "+v"(v1) :: "memory");
                __builtin_amdgcn_sched_barrier(0);
                if ((u32)(v1 >> 32) == want) { got = v1; break; }
                asm volatile("global_load_dwordx2 %0, %1, off sc0"
                             : "=&v"(v1) : "v"(mslot) : "memory");
                asm volatile("s_waitcnt vmcnt(2)" : "+v"(v2) :: "memory");
                __builtin_amdgcn_sched_barrier(0);
                if ((u32)(v2 >> 32) == want) { got = v2; break; }
                asm volatile("global_load_dwordx2 %0, %1, off sc0"
                             : "=&v"(v2) : "v"(mslot) : "memory");
                // rare backstop: correct under ANY placement; drains the
                // pipeline (implicit vmcnt(0)) so only run every 8 misses.
                if (++miss == 8) {
                    miss = 0;
                    u64 vc = __hip_atomic_load(cslot, __ATOMIC_RELAXED,
                                               __HIP_MEMORY_SCOPE_AGENT);
                    if ((u32)(vc >> 32) == want) { got = vc; break; }
                }
            }
            hval = __uint_as_float((u32)got);
        }

        // xw load AFTER the poll (keeps hand-counted vmcnt honest);
        // overlaps the dot below, consumed in the funnel.
        float xwv = 0.f;
        if (tid < 64)
            xwv = xw[((size_t)(dir * L) + t) * G4H + wg * 64 + l];

        // ---- dot: row l over slice wv via readlane broadcast, 4 accs ----
        float a0 = 0.f, a1 = 0.f, a2 = 0.f, a3 = 0.f;
#pragma unroll
        for (int i = 0; i < 64; i += 4) {
            float h0v = __uint_as_float((u32)__builtin_amdgcn_readlane(
                            (int)__float_as_uint(hval), i));
            float h1v = __uint_as_float((u32)__builtin_amdgcn_readlane(
                            (int)__float_as_uint(hval), i + 1));
            float h2v = __uint_as_float((u32)__builtin_amdgcn_readlane(
                            (int)__float_as_uint(hval), i + 2));
            float h3v = __uint_as_float((u32)__builtin_amdgcn_readlane(
                            (int)__float_as_uint(hval), i + 3));
            a0 = fmaf(w[i],     h0v, a0);
            a1 = fmaf(w[i + 1], h1v, a1);
            a2 = fmaf(w[i + 2], h2v, a2);
            a3 = fmaf(w[i + 3], h3v, a3);
        }
        PB(par, wv, l) = (a0 + a1) + (a2 + a3);
        __syncthreads();

        // ---- wave0 funnel tail: reduce 8 partials, gates, publish ----
        if (tid < 64) {
            float tot = 0.f;
#pragma unroll
            for (int p = 0; p < 8; ++p) tot += PB(par, p, l);
            float pre = tot + xwv;
            float aa = (g == 2) ? 2.f * pre : pre;       // tanh = 2*sig(2x)-1
            float sg = 1.f / (1.f + __expf(-aa));
            float vg = (g == 2) ? (2.f * sg - 1.f) : sg;
            float gi = __shfl(vg, j);
            float gf = __shfl(vg, 16 + j);
            float gg = __shfl(vg, 32 + j);
            float go = __shfl(vg, 48 + j);
            if (tid < 16) {
                c = gf * c + gi * gg;
                float th = 2.f / (1.f + __expf(-2.f * c)) - 1.f;
                float hout = go * th;
                u64 e = ((u64)(u32)s << 32) | (u64)__float_as_uint(hout);
                const u64* ma = mird + par * 512 + wg * 16 + tid;
                // mirror first: fast local-L2 visibility for co-XCD peers
                asm volatile("global_store_dwordx2 %0, %1, off sc0"
                             :: "v"(ma), "v"(e) : "memory");
                // canonical: device-scope, correct under any placement
                __hip_atomic_store(hb + par * 512 + wg * 16 + tid, e,
                                   __ATOMIC_RELAXED, __HIP_MEMORY_SCOPE_AGENT);
                histd[(size_t)t * H + wg * 16 + tid] = hout;
            }
        }
        // pbuf parity double-buffer + the single barrier covers reuse
    }
#undef PB
}

// ---------------------------------------------------------------------------
// K3: feats[t][tag] = b_out[tag] + concat(hf,hb)[t] . w_out[tag]   (f32)
__global__ void k3_feats(const float* __restrict__ hist,
                         const float* __restrict__ wout,
                         const float* __restrict__ bout,
                         float* __restrict__ feats) {
    int t = blockIdx.x;
    int tid = threadIdx.x;
    int tag = tid >> 4;       // [0,20)
    int part = tid & 15;
    const float* h0p = hist + (size_t)t * H;
    const float* h1p = hist + (size_t)L * H + (size_t)t * H;
    int j0 = part * 64;
    float acc = 0.f;
    for (int jj = 0; jj < 64; jj += 4) {
        int j = j0 + jj;
        float4 w4 = *(const float4*)(wout + (size_t)tag * (2 * H) + j);
        float4 h4 = (j < H) ? *(const float4*)(h0p + j)
                            : *(const float4*)(h1p + (j - H));
        acc = fmaf(w4.x, h4.x, fmaf(w4.y, h4.y,
              fmaf(w4.z, h4.z, fmaf(w4.w, h4.w, acc))));
    }
    acc += __shfl_xor(acc, 8, 16);
    acc += __shfl_xor(acc, 4, 16);
    acc += __shfl_xor(acc, 2, 16);
    acc += __shfl_xor(acc, 1, 16);
    if (part == 0) feats[(size_t)t * NTAGS + tag] = acc + bout[tag];
}

// ---------------------------------------------------------------------------
// K4: Viterbi + backtrack, one wave. Batched shfls + index-carrying tree-max
// (exact first-max semantics).
__global__ void k4_viterbi(const float* __restrict__ feats,
                           const float* __restrict__ trans,
                           int* __restrict__ out) {
    __shared__ unsigned char bp[L * NTAGS];
    int lane = threadIdx.x;           // 64 threads
    bool act = lane < NTAGS;

    float trl[NTAGS];
#pragma unroll
    for (int p = 0; p < NTAGS; ++p)
        trl[p] = act ? trans[lane * NTAGS + p] : -1.0e30f;

    float fv = (lane == START_TAG) ? 0.f : -10000.f;
    float nf = act ? feats[lane] : 0.f;

    for (int t = 0; t < L; ++t) {
        float f = nf;
        if (act && t + 1 < L) nf = feats[(size_t)(t + 1) * NTAGS + lane];
        float tv[NTAGS];
        int   ti[NTAGS];
#pragma unroll
        for (int p = 0; p < NTAGS; ++p) {
            tv[p] = __shfl(fv, p) + trl[p];
            ti[p] = p;
        }
#pragma unroll
        for (int p = 0; p < 4; ++p) {
            bool take = (tv[p + 16] > tv[p]) ||
                        (tv[p + 16] == tv[p] && ti[p + 16] < ti[p]);
            if (take) { tv[p] = tv[p + 16]; ti[p] = ti[p + 16]; }
        }
#pragma unroll
        for (int w = 8; w >= 1; w >>= 1)
#pragma unroll
            for (int p = 0; p < 16; ++p) if (p < w) {
                bool take = (tv[p + w] > tv[p]) ||
                            (tv[p + w] == tv[p] && ti[p + w] < ti[p]);
                if (take) { tv[p] = tv[p + w]; ti[p] = ti[p + w]; }
            }
        fv = tv[0] + f;
        if (act) bp[t * NTAGS + lane] = (unsigned char)ti[0];
    }

    float ts = act ? fv + trans[STOP_TAG * NTAGS + lane] : -1.0e30f;
    int bi = lane;
#pragma unroll
    for (int off = 32; off; off >>= 1) {
        float ov = __shfl_down(ts, off);
        int   oi = __shfl_down(bi, off);
        if (ov > ts) { ts = ov; bi = oi; }
    }
    if (lane == 0) {
        int tag = bi;
        out[L - 1] = tag;
        for (int t = L - 1; t >= 1; --t) {
            tag = bp[t * NTAGS + tag];
            out[t - 1] = tag;
        }
    }
}

// ---------------------------------------------------------------------------
extern "C" void kernel_launch(void* const* d_in, const int* in_sizes, int n_in,
                              void* d_out, int out_size, void* d_ws, size_t ws_size,
                              hipStream_t stream) {
    const int*   sentence = (const int*)d_in[0];
    const float* embed    = (const float*)d_in[1];
    const float* wih_f    = (const float*)d_in[2];
    const float* whh_f    = (const float*)d_in[3];
    const float* bih_f    = (const float*)d_in[4];
    const float* bhh_f    = (const float*)d_in[5];
    const float* wih_b    = (const float*)d_in[6];
    const float* whh_b    = (const float*)d_in[7];
    const float* bih_b    = (const float*)d_in[8];
    const float* bhh_b    = (const float*)d_in[9];
    const float* h0       = (const float*)d_in[10];
    const float* c0       = (const float*)d_in[11];
    const float* wout     = (const float*)d_in[12];
    const float* bout     = (const float*)d_in[13];
    const float* trans    = (const float*)d_in[14];
    int* out = (int*)d_out;

    char* ws = (char*)d_ws;
    float* xw    = (float*)(ws + OFF_XW);
    float* hist  = (float*)(ws + OFF_HIST);
    float* feats = (float*)(ws + OFF_FEATS);
    u64*   hbuf  = (u64*)(ws + OFF_HBUF);
    u64*   mir   = (u64*)(ws + OFF_FEATS);            // dead until k3
    int*   cntX  = (int*)(ws + OFF_FEATS + 16384);
    int*   claimed = cntX + 8;

    k0_init<<<1, 256, 0, stream>>>(mir);
    k1_xw<<<dim3(32, 8, 2), 256, 0, stream>>>(sentence, embed, wih_f, wih_b,
                                              bih_f, bhh_f, bih_b, bhh_b, xw);
    k2_lstm<<<256, 512, 0, stream>>>(whh_f, whh_b, h0, c0, xw, hist, hbuf,
                                     mir, cntX, claimed);
    k3_feats<<<L, 320, 0, stream>>>(hist, wout, bout, feats);
    k4_viterbi<<<1, 64, 0, stream>>>(feats, trans, out);
}

// Round 5
// 1922.055 us; speedup vs baseline: 1.0436x; 1.0436x over previous
//
#include <hip/hip_runtime.h>
#include <math.h>

typedef unsigned long long u64;
typedef unsigned int u32;

// Problem constants
#define L 512
#define E 300
#define H 512          // per-direction hidden
#define G4H 2048       // 4*H
#define NTAGS 20
#define START_TAG 18
#define STOP_TAG 19

#define KC 100         // k1 K-chunk (300 = 3*100)

// Workspace layout (bytes) -- footprint UNCHANGED from the verified baseline
#define OFF_XW    0u          // f32 [2][512][2048] (permuted cols) = 8388608
#define OFF_HIST  8388608u    // f32 [2][512][512]  = 2097152
#define OFF_HBUF  10485760u   // u64 [2][2][512] canonical h slots = 16384
#define OFF_FEATS 10502144u   // f32 [512][20] = 40960. DEAD until k3 ->
                              // reused during k2 as mirror u64 [2][2][512]
                              // (k3 overwrites it afterwards -> k0 re-zeros
                              // each replay so stale feats bits can't alias
                              // a valid tag).

// ---------------------------------------------------------------------------
// K0: zero the mirror (must run before every k2 replay).
__global__ void k0_init(u64* __restrict__ z) {
    int t = threadIdx.x;
#pragma unroll
    for (int i = 0; i < 8; ++i) z[t * 8 + i] = 0;   // 256*8 = 2048 u64
}

// ---------------------------------------------------------------------------
// K1: tiled GEMM  xw[dir][t][pos(n)] = embed[sent[t]] . wih[n] + bias(n).
// (unchanged from verified baseline)
__global__ __launch_bounds__(256) void k1_xw(
    const int* __restrict__ sentence, const float* __restrict__ embed,
    const float* __restrict__ wih_f, const float* __restrict__ wih_b,
    const float* __restrict__ bih_f, const float* __restrict__ bhh_f,
    const float* __restrict__ bih_b, const float* __restrict__ bhh_b,
    float* __restrict__ xw) {
    __shared__ float wST[KC][68];   // [k][n]
    __shared__ float xST[KC][68];   // [k][t]
    __shared__ int   sT[64];

    const int tid = threadIdx.x;
    const int tx = tid & 15;        // t micro index
    const int ty = tid >> 4;        // n micro index
    const int n_base = blockIdx.x * 64;
    const int t_base = blockIdx.y * 64;
    const int dir = blockIdx.z;
    const float* wih = dir ? wih_b : wih_f;
    const float* bih = dir ? bih_b : bih_f;
    const float* bhh = dir ? bhh_b : bhh_f;

    if (tid < 64) sT[tid] = sentence[t_base + tid];
    __syncthreads();

    float acc[4][4];
#pragma unroll
    for (int i = 0; i < 4; ++i)
#pragma unroll
        for (int j = 0; j < 4; ++j) acc[i][j] = 0.f;

    for (int kc = 0; kc < E; kc += KC) {
#pragma unroll
        for (int i = 0; i < 25; ++i) {
            int idx = i * 256 + tid;          // < 6400
            int row = idx / KC, col = idx % KC;
            wST[col][row] = wih[(size_t)(n_base + row) * E + kc + col];
        }
#pragma unroll
        for (int i = 0; i < 25; ++i) {
            int idx = i * 256 + tid;
            int trow = idx / KC, col = idx % KC;
            xST[col][trow] = embed[(size_t)sT[trow] * E + kc + col];
        }
        __syncthreads();

#pragma unroll 4
        for (int k = 0; k < KC; ++k) {
            float4 wv4 = *(const float4*)&wST[k][ty * 4];
            float4 xv4 = *(const float4*)&xST[k][tx * 4];
            float wv[4] = {wv4.x, wv4.y, wv4.z, wv4.w};
            float xv[4] = {xv4.x, xv4.y, xv4.z, xv4.w};
#pragma unroll
            for (int i = 0; i < 4; ++i)
#pragma unroll
                for (int j = 0; j < 4; ++j)
                    acc[i][j] = fmaf(wv[i], xv[j], acc[i][j]);
        }
        __syncthreads();
    }

#pragma unroll
    for (int i = 0; i < 4; ++i) {
        int n = n_base + ty * 4 + i;
        float b = bih[n] + bhh[n];
        int u = n & (H - 1), g = n >> 9;
        int pos = (u >> 4) * 64 + g * 16 + (u & 15);   // gate-major in block
#pragma unroll
        for (int j = 0; j < 4; ++j) {
            int t = t_base + tx * 4 + j;
            xw[((size_t)(dir * L) + t) * G4H + pos] = acc[i][j] + b;
        }
    }
}

// ---------------------------------------------------------------------------
// K2: bidirectional LSTM recurrence, XCD-clustered by DISPATCH ORDER.
//
// r4 post-mortem: perf degraded monotonically as the agent-scope backstop
// got rarer (854 pure-agent / 922 backstop-every-iter / 1459 every-8) ->
// the sc0 mirror NEVER delivered; placement via s_getreg(XCC_ID) was
// garbage -> workers scattered -> remote consumers' L2s served stale
// mirror lines forever. (FETCH_SIZE dropping was stale-hit traffic, not
// proof of co-location -- ERRATA on my r3 read.)
//
// This round: placement via the HW-verified dispatch model behind the
// blockIdx%8 swizzle technique: at 1 WG/CU (86KB LDS) with grid=256, the
// CP round-robins WGs over XCDs, so XCD = blockIdx%8. bid%8==0 -> the 32
// fwd workers (all XCD0); bid%8==1 -> bwd (XCD1); other 192 WGs exit at
// once. Deterministic, no atomics, every slot covered -> no deadlock.
//
// Poll: 3-deep pipelined sc0 mirror rotation (sampling ~L2RT/3). TIMEOUT
// fallback: after 8 fruitless rotations, switch to the baseline-proven
// agent-scope 3-deep rotation (sc0 sc1) for the rest of the step. Good
// case: fallback never runs, zero drain on the fast path. Bad case: ~2K
// cy/step wasted, still finishes (and falsifies the dispatch model).
#define SHM_U64 10800   // 86400 B LDS: 2 WGs/CU impossible (172800 > 160K)
#define NROT 8          // mirror rotations before canonical fallback

__global__ __launch_bounds__(512, 1) void k2_lstm(
    const float* __restrict__ whh_f, const float* __restrict__ whh_b,
    const float* __restrict__ h0, const float* __restrict__ c0,
    const float* __restrict__ xw, float* __restrict__ hist,
    u64* __restrict__ hbuf, u64* __restrict__ mir) {

    __shared__ u64 shm[SHM_U64];
    float* pbuf = (float*)(shm + 8);           // [2][8][68] floats = 4352 B
#define PB(p, w, l) pbuf[(((p) * 8 + (w)) * 68) + (l)]

    const int bid = blockIdx.x;
    const int sub = bid & 7;        // XCD id under round-robin dispatch
    if (sub >= 2) return;           // 192 spare WGs exit (no barriers yet)
    const int dir = sub;            // XCD0 -> fwd, XCD1 -> bwd
    const int wg  = bid >> 3;       // 0..31 within the direction

    const int tid = threadIdx.x;
    if (tid == 0) shm[SHM_U64 - 1] = 0;   // keep the LDS pad alive
    const int wv  = tid >> 6;       // wave id = dot k-slice
    const int l   = tid & 63;
    const int g   = l >> 4;         // gate: 0=i 1=f 2=g 3=o
    const int j   = l & 15;         // unit within WG
    const int grow = g * H + wg * 16 + j;

    const float* whh = dir ? whh_b : whh_f;
    float* histd = hist + (size_t)dir * L * H;
    u64* hb   = hbuf + dir * 1024;  // canonical [parity][512]
    u64* mird = mir  + dir * 1024;  // mirror    [parity][512]

    // this lane's 64 Whh weights (row grow, slice wv) -> regs
    float w[64];
    {
        const float* wp = whh + (size_t)grow * H + wv * 64;
#pragma unroll
        for (int i = 0; i < 64; i += 4) {
            float4 v = *(const float4*)(wp + i);
            w[i] = v.x; w[i+1] = v.y; w[i+2] = v.z; w[i+3] = v.w;
        }
    }

    // c state lives on wave0 lanes 0..15 (unit = wg*16 + tid)
    float c = (tid < 16) ? c0[dir * H + wg * 16 + tid] : 0.f;

    for (int s = 1; s <= L; ++s) {
        const int t = dir ? (L - s) : (s - 1);
        const int par = s & 1;

        // ---- acquire h_{s-1}[tid] ----
        float hval;
        if (s == 1) {
            hval = h0[dir * H + tid];
        } else {
            const u32 want = (u32)(s - 1);
            const u64* mslot = mird + ((s - 1) & 1) * 512 + tid;
            const u64* cslot = hb + ((s - 1) & 1) * 512 + tid;
            u64 v0, v1, v2, got;
            bool found = false;
            // fast path: 3-deep pipelined sc0 mirror poll (XCD-local L2)
            asm volatile("global_load_dwordx2 %0, %3, off sc0\n\t"
                         "global_load_dwordx2 %1, %3, off sc0\n\t"
                         "global_load_dwordx2 %2, %3, off sc0"
                         : "=&v"(v0), "=&v"(v1), "=&v"(v2)
                         : "v"(mslot) : "memory");
            for (int rot = 0; rot < NROT; ++rot) {
                asm volatile("s_waitcnt vmcnt(2)" : "+v"(v0) :: "memory");
                __builtin_amdgcn_sched_barrier(0);
                if ((u32)(v0 >> 32) == want) { got = v0; found = true; break; }
                asm volatile("global_load_dwordx2 %0, %1, off sc0"
                             : "=&v"(v0) : "v"(mslot) : "memory");
                asm volatile("s_waitcnt vmcnt(2)" : "+v"(v1) :: "memory");
                __builtin_amdgcn_sched_barrier(0);
                if ((u32)(v1 >> 32) == want) { got = v1; found = true; break; }
                asm volatile("global_load_dwordx2 %0, %1, off sc0"
                             : "=&v"(v1) : "v"(mslot) : "memory");
                asm volatile("s_waitcnt vmcnt(2)" : "+v"(v2) :: "memory");
                __builtin_amdgcn_sched_barrier(0);
                if ((u32)(v2 >> 32) == want) { got = v2; found = true; break; }
                asm volatile("global_load_dwordx2 %0, %1, off sc0"
                             : "=&v"(v2) : "v"(mslot) : "memory");
            }
            if (!found) {
                // timeout fallback: baseline-proven agent-scope 3-deep
                // rotation (sc0 sc1 -> coherence point), until found.
                asm volatile("global_load_dwordx2 %0, %3, off sc0 sc1\n\t"
                             "global_load_dwordx2 %1, %3, off sc0 sc1\n\t"
                             "global_load_dwordx2 %2, %3, off sc0 sc1"
                             : "=&v"(v0), "=&v"(v1), "=&v"(v2)
                             : "v"(cslot) : "memory");
                while (true) {
                    asm volatile("s_waitcnt vmcnt(2)" : "+v"(v0) :: "memory");
                    __builtin_amdgcn_sched_barrier(0);
                    if ((u32)(v0 >> 32) == want) { got = v0; break; }
                    asm volatile("global_load_dwordx2 %0, %1, off sc0 sc1"
                                 : "=&v"(v0) : "v"(cslot) : "memory");
                    asm volatile("s_waitcnt vmcnt(2)" : "+v"(v1) :: "memory");
                    __builtin_amdgcn_sched_barrier(0);
                    if ((u32)(v1 >> 32) == want) { got = v1; break; }
                    asm volatile("global_load_dwordx2 %0, %1, off sc0 sc1"
                                 : "=&v"(v1) : "v"(cslot) : "memory");
                    asm volatile("s_waitcnt vmcnt(2)" : "+v"(v2) :: "memory");
                    __builtin_amdgcn_sched_barrier(0);
                    if ((u32)(v2 >> 32) == want) { got = v2; break; }
                    asm volatile("global_load_dwordx2 %0, %1, off sc0 sc1"
                                 : "=&v"(v2) : "v"(cslot) : "memory");
                }
            }
            hval = __uint_as_float((u32)got);
        }

        // xw load AFTER the poll (keeps hand-counted vmcnt honest);
        // overlaps the dot below, consumed in the funnel.
        float xwv = 0.f;
        if (tid < 64)
            xwv = xw[((size_t)(dir * L) + t) * G4H + wg * 64 + l];

        // ---- dot: row l over slice wv via readlane broadcast, 4 accs ----
        float a0 = 0.f, a1 = 0.f, a2 = 0.f, a3 = 0.f;
#pragma unroll
        for (int i = 0; i < 64; i += 4) {
            float h0v = __uint_as_float((u32)__builtin_amdgcn_readlane(
                            (int)__float_as_uint(hval), i));
            float h1v = __uint_as_float((u32)__builtin_amdgcn_readlane(
                            (int)__float_as_uint(hval), i + 1));
            float h2v = __uint_as_float((u32)__builtin_amdgcn_readlane(
                            (int)__float_as_uint(hval), i + 2));
            float h3v = __uint_as_float((u32)__builtin_amdgcn_readlane(
                            (int)__float_as_uint(hval), i + 3));
            a0 = fmaf(w[i],     h0v, a0);
            a1 = fmaf(w[i + 1], h1v, a1);
            a2 = fmaf(w[i + 2], h2v, a2);
            a3 = fmaf(w[i + 3], h3v, a3);
        }
        PB(par, wv, l) = (a0 + a1) + (a2 + a3);
        __syncthreads();

        // ---- wave0 funnel tail: reduce 8 partials, gates, publish ----
        if (tid < 64) {
            float tot = 0.f;
#pragma unroll
            for (int p = 0; p < 8; ++p) tot += PB(par, p, l);
            float pre = tot + xwv;
            float aa = (g == 2) ? 2.f * pre : pre;       // tanh = 2*sig(2x)-1
            float sg = 1.f / (1.f + __expf(-aa));
            float vg = (g == 2) ? (2.f * sg - 1.f) : sg;
            float gi = __shfl(vg, j);
            float gf = __shfl(vg, 16 + j);
            float gg = __shfl(vg, 32 + j);
            float go = __shfl(vg, 48 + j);
            if (tid < 16) {
                c = gf * c + gi * gg;
                float th = 2.f / (1.f + __expf(-2.f * c)) - 1.f;
                float hout = go * th;
                u64 e = ((u64)(u32)s << 32) | (u64)__float_as_uint(hout);
                const u64* ma = mird + par * 512 + wg * 16 + tid;
                const u64* ca = hb + par * 512 + wg * 16 + tid;
                // mirror first: fast local-L2 visibility for co-XCD peers
                asm volatile("global_store_dwordx2 %0, %1, off sc0"
                             :: "v"(ma), "v"(e) : "memory");
                // canonical: through the coherence point, any placement
                asm volatile("global_store_dwordx2 %0, %1, off sc0 sc1"
                             :: "v"(ca), "v"(e) : "memory");
                histd[(size_t)t * H + wg * 16 + tid] = hout;
            }
        }
        // pbuf parity double-buffer + the single barrier covers reuse
    }
#undef PB
}

// ---------------------------------------------------------------------------
// K3: feats[t][tag] = b_out[tag] + concat(hf,hb)[t] . w_out[tag]   (f32)
__global__ void k3_feats(const float* __restrict__ hist,
                         const float* __restrict__ wout,
                         const float* __restrict__ bout,
                         float* __restrict__ feats) {
    int t = blockIdx.x;
    int tid = threadIdx.x;
    int tag = tid >> 4;       // [0,20)
    int part = tid & 15;
    const float* h0p = hist + (size_t)t * H;
    const float* h1p = hist + (size_t)L * H + (size_t)t * H;
    int j0 = part * 64;
    float acc = 0.f;
    for (int jj = 0; jj < 64; jj += 4) {
        int j = j0 + jj;
        float4 w4 = *(const float4*)(wout + (size_t)tag * (2 * H) + j);
        float4 h4 = (j < H) ? *(const float4*)(h0p + j)
                            : *(const float4*)(h1p + (j - H));
        acc = fmaf(w4.x, h4.x, fmaf(w4.y, h4.y,
              fmaf(w4.z, h4.z, fmaf(w4.w, h4.w, acc))));
    }
    acc += __shfl_xor(acc, 8, 16);
    acc += __shfl_xor(acc, 4, 16);
    acc += __shfl_xor(acc, 2, 16);
    acc += __shfl_xor(acc, 1, 16);
    if (part == 0) feats[(size_t)t * NTAGS + tag] = acc + bout[tag];
}

// ---------------------------------------------------------------------------
// K4: Viterbi + backtrack, one wave. Batched shfls + index-carrying tree-max
// (exact first-max semantics).
__global__ void k4_viterbi(const float* __restrict__ feats,
                           const float* __restrict__ trans,
                           int* __restrict__ out) {
    __shared__ unsigned char bp[L * NTAGS];
    int lane = threadIdx.x;           // 64 threads
    bool act = lane < NTAGS;

    float trl[NTAGS];
#pragma unroll
    for (int p = 0; p < NTAGS; ++p)
        trl[p] = act ? trans[lane * NTAGS + p] : -1.0e30f;

    float fv = (lane == START_TAG) ? 0.f : -10000.f;
    float nf = act ? feats[lane] : 0.f;

    for (int t = 0; t < L; ++t) {
        float f = nf;
        if (act && t + 1 < L) nf = feats[(size_t)(t + 1) * NTAGS + lane];
        float tv[NTAGS];
        int   ti[NTAGS];
#pragma unroll
        for (int p = 0; p < NTAGS; ++p) {
            tv[p] = __shfl(fv, p) + trl[p];
            ti[p] = p;
        }
#pragma unroll
        for (int p = 0; p < 4; ++p) {
            bool take = (tv[p + 16] > tv[p]) ||
                        (tv[p + 16] == tv[p] && ti[p + 16] < ti[p]);
            if (take) { tv[p] = tv[p + 16]; ti[p] = ti[p + 16]; }
        }
#pragma unroll
        for (int w = 8; w >= 1; w >>= 1)
#pragma unroll
            for (int p = 0; p < 16; ++p) if (p < w) {
                bool take = (tv[p + w] > tv[p]) ||
                            (tv[p + w] == tv[p] && ti[p + w] < ti[p]);
                if (take) { tv[p] = tv[p + w]; ti[p] = ti[p + w]; }
            }
        fv = tv[0] + f;
        if (act) bp[t * NTAGS + lane] = (unsigned char)ti[0];
    }

    float ts = act ? fv + trans[STOP_TAG * NTAGS + lane] : -1.0e30f;
    int bi = lane;
#pragma unroll
    for (int off = 32; off; off >>= 1) {
        float ov = __shfl_down(ts, off);
        int   oi = __shfl_down(bi, off);
        if (ov > ts) { ts = ov; bi = oi; }
    }
    if (lane == 0) {
        int tag = bi;
        out[L - 1] = tag;
        for (int t = L - 1; t >= 1; --t) {
            tag = bp[t * NTAGS + tag];
            out[t - 1] = tag;
        }
    }
}

// ---------------------------------------------------------------------------
extern "C" void kernel_launch(void* const* d_in, const int* in_sizes, int n_in,
                              void* d_out, int out_size, void* d_ws, size_t ws_size,
                              hipStream_t stream) {
    const int*   sentence = (const int*)d_in[0];
    const float* embed    = (const float*)d_in[1];
    const float* wih_f    = (const float*)d_in[2];
    const float* whh_f    = (const float*)d_in[3];
    const float* bih_f    = (const float*)d_in[4];
    const float* bhh_f    = (const float*)d_in[5];
    const float* wih_b    = (const float*)d_in[6];
    const float* whh_b    = (const float*)d_in[7];
    const float* bih_b    = (const float*)d_in[8];
    const float* bhh_b    = (const float*)d_in[9];
    const float* h0       = (const float*)d_in[10];
    const float* c0       = (const float*)d_in[11];
    const float* wout     = (const float*)d_in[12];
    const float* bout     = (const float*)d_in[13];
    const float* trans    = (const float*)d_in[14];
    int* out = (int*)d_out;

    char* ws = (char*)d_ws;
    float* xw    = (float*)(ws + OFF_XW);
    float* hist  = (float*)(ws + OFF_HIST);
    float* feats = (float*)(ws + OFF_FEATS);
    u64*   hbuf  = (u64*)(ws + OFF_HBUF);
    u64*   mir   = (u64*)(ws + OFF_FEATS);            // dead until k3

    k0_init<<<1, 256, 0, stream>>>(mir);
    k1_xw<<<dim3(32, 8, 2), 256, 0, stream>>>(sentence, embed, wih_f, wih_b,
                                              bih_f, bhh_f, bih_b, bhh_b, xw);
    k2_lstm<<<256, 512, 0, stream>>>(whh_f, whh_b, h0, c0, xw, hist, hbuf, mir);
    k3_feats<<<L, 320, 0, stream>>>(hist, wout, bout, feats);
    k4_viterbi<<<1, 64, 0, stream>>>(feats, trans, out);
}

// Round 6
// 1582.591 us; speedup vs baseline: 1.2675x; 1.2145x over previous
//
#include <hip/hip_runtime.h>
#include <math.h>

typedef unsigned long long u64;
typedef unsigned int u32;

// Problem constants
#define L 512
#define E 300
#define H 512          // per-direction hidden
#define G4H 2048       // 4*H
#define NTAGS 20
#define START_TAG 18
#define STOP_TAG 19

#define KC 100         // k1 K-chunk (300 = 3*100)

// Workspace layout (bytes) -- footprint UNCHANGED from the verified baseline
#define OFF_XW    0u          // f32 [2][512][2048] (permuted cols) = 8388608
#define OFF_HIST  8388608u    // f32 [2][512][512]  = 2097152
#define OFF_HBUF  10485760u   // u64 [2][2][512] canonical h slots = 16384
#define OFF_FEATS 10502144u   // f32 [512][20] = 40960. DEAD until k3 ->
                              // reused during k2 as mirror u64 [2][2][512]
                              // (k0 re-zeros each replay so stale feats bits
                              // can't alias a valid tag).

// ---------------------------------------------------------------------------
// K0: zero the mirror (must run before every k2 replay).
__global__ void k0_init(u64* __restrict__ z) {
    int t = threadIdx.x;
#pragma unroll
    for (int i = 0; i < 8; ++i) z[t * 8 + i] = 0;   // 256*8 = 2048 u64
}

// ---------------------------------------------------------------------------
// K1: tiled GEMM  xw[dir][t][pos(n)] = embed[sent[t]] . wih[n] + bias(n).
// (unchanged from verified baseline)
__global__ __launch_bounds__(256) void k1_xw(
    const int* __restrict__ sentence, const float* __restrict__ embed,
    const float* __restrict__ wih_f, const float* __restrict__ wih_b,
    const float* __restrict__ bih_f, const float* __restrict__ bhh_f,
    const float* __restrict__ bih_b, const float* __restrict__ bhh_b,
    float* __restrict__ xw) {
    __shared__ float wST[KC][68];   // [k][n]
    __shared__ float xST[KC][68];   // [k][t]
    __shared__ int   sT[64];

    const int tid = threadIdx.x;
    const int tx = tid & 15;        // t micro index
    const int ty = tid >> 4;        // n micro index
    const int n_base = blockIdx.x * 64;
    const int t_base = blockIdx.y * 64;
    const int dir = blockIdx.z;
    const float* wih = dir ? wih_b : wih_f;
    const float* bih = dir ? bih_b : bih_f;
    const float* bhh = dir ? bhh_b : bhh_f;

    if (tid < 64) sT[tid] = sentence[t_base + tid];
    __syncthreads();

    float acc[4][4];
#pragma unroll
    for (int i = 0; i < 4; ++i)
#pragma unroll
        for (int j = 0; j < 4; ++j) acc[i][j] = 0.f;

    for (int kc = 0; kc < E; kc += KC) {
#pragma unroll
        for (int i = 0; i < 25; ++i) {
            int idx = i * 256 + tid;          // < 6400
            int row = idx / KC, col = idx % KC;
            wST[col][row] = wih[(size_t)(n_base + row) * E + kc + col];
        }
#pragma unroll
        for (int i = 0; i < 25; ++i) {
            int idx = i * 256 + tid;
            int trow = idx / KC, col = idx % KC;
            xST[col][trow] = embed[(size_t)sT[trow] * E + kc + col];
        }
        __syncthreads();

#pragma unroll 4
        for (int k = 0; k < KC; ++k) {
            float4 wv4 = *(const float4*)&wST[k][ty * 4];
            float4 xv4 = *(const float4*)&xST[k][tx * 4];
            float wv[4] = {wv4.x, wv4.y, wv4.z, wv4.w};
            float xv[4] = {xv4.x, xv4.y, xv4.z, xv4.w};
#pragma unroll
            for (int i = 0; i < 4; ++i)
#pragma unroll
                for (int j = 0; j < 4; ++j)
                    acc[i][j] = fmaf(wv[i], xv[j], acc[i][j]);
        }
        __syncthreads();
    }

#pragma unroll
    for (int i = 0; i < 4; ++i) {
        int n = n_base + ty * 4 + i;
        float b = bih[n] + bhh[n];
        int u = n & (H - 1), g = n >> 9;
        int pos = (u >> 4) * 64 + g * 16 + (u & 15);   // gate-major in block
#pragma unroll
        for (int j = 0; j < 4; ++j) {
            int t = t_base + tx * 4 + j;
            xw[((size_t)(dir * L) + t) * G4H + pos] = acc[i][j] + b;
        }
    }
}

// ---------------------------------------------------------------------------
// K2: bidirectional LSTM recurrence, XCD-clustered.
//
// r5 post-mortem: the sc0-only mirror poll was served by the CONSUMER'S OWN
// vL1D -- the first miss installs the stale line (tag=0) and every later
// sc0 poll hits it forever, regardless of producer placement. One mechanism
// explains all three mirror failures (r3/r4/r5). Fix: poll = buffer_inv sc0
// (gfx940-family L1 invalidate; L2 untouched) + PLAIN coalesced load ->
// guaranteed L1 miss -> served from the XCD-local L2, which the producer's
// write-through store updated if co-located. L1-invalidate collateral in
// this kernel is ~nil (xw streamed once, whh in regs, pbuf is LDS).
//
// Placement: dispatch-order model behind the HW-verified %8 swizzle: at
// 1 WG/CU (86KB LDS) with grid=256, XCD = blockIdx%8. bid%8==0 -> 32 fwd
// workers (XCD0); bid%8==1 -> bwd (XCD1); other 192 WGs exit.
//
// Failure containment (r5 cost 512 timeouts): sticky mirror-kill -- after
// 3 consecutive timed-out steps a thread permanently switches to the
// baseline-proven agent-scope rotation. Worst case ~ baseline + startup.
#define SHM_U64 10800   // 86400 B LDS: 2 WGs/CU impossible (172800 > 160K)
#define NROT 6          // mirror samples per step before timeout

__global__ __launch_bounds__(512, 1) void k2_lstm(
    const float* __restrict__ whh_f, const float* __restrict__ whh_b,
    const float* __restrict__ h0, const float* __restrict__ c0,
    const float* __restrict__ xw, float* __restrict__ hist,
    u64* __restrict__ hbuf, u64* __restrict__ mir) {

    __shared__ u64 shm[SHM_U64];
    float* pbuf = (float*)(shm + 8);           // [2][8][68] floats = 4352 B
#define PB(p, w, l) pbuf[(((p) * 8 + (w)) * 68) + (l)]

    const int bid = blockIdx.x;
    const int sub = bid & 7;        // XCD id under round-robin dispatch
    if (sub >= 2) return;           // 192 spare WGs exit (no barriers yet)
    const int dir = sub;            // XCD0 -> fwd, XCD1 -> bwd
    const int wg  = bid >> 3;       // 0..31 within the direction

    const int tid = threadIdx.x;
    if (tid == 0) shm[SHM_U64 - 1] = 0;   // keep the LDS pad alive
    const int wv  = tid >> 6;       // wave id = dot k-slice
    const int l   = tid & 63;
    const int g   = l >> 4;         // gate: 0=i 1=f 2=g 3=o
    const int j   = l & 15;         // unit within WG
    const int grow = g * H + wg * 16 + j;

    const float* whh = dir ? whh_b : whh_f;
    float* histd = hist + (size_t)dir * L * H;
    u64* hb   = hbuf + dir * 1024;  // canonical [parity][512]
    u64* mird = mir  + dir * 1024;  // mirror    [parity][512]

    // this lane's 64 Whh weights (row grow, slice wv) -> regs
    float w[64];
    {
        const float* wp = whh + (size_t)grow * H + wv * 64;
#pragma unroll
        for (int i = 0; i < 64; i += 4) {
            float4 v = *(const float4*)(wp + i);
            w[i] = v.x; w[i+1] = v.y; w[i+2] = v.z; w[i+3] = v.w;
        }
    }

    // c state lives on wave0 lanes 0..15 (unit = wg*16 + tid)
    float c = (tid < 16) ? c0[dir * H + wg * 16 + tid] : 0.f;

    int miss_streak = 0;            // consecutive mirror-timeout steps
    bool mdead = false;             // sticky: mirror proven useless

    for (int s = 1; s <= L; ++s) {
        const int t = dir ? (L - s) : (s - 1);
        const int par = s & 1;

        // ---- acquire h_{s-1}[tid] ----
        float hval;
        if (s == 1) {
            hval = h0[dir * H + tid];
        } else {
            const u32 want = (u32)(s - 1);
            const u64* mslot = mird + ((s - 1) & 1) * 512 + tid;
            const u64* cslot = hb + ((s - 1) & 1) * 512 + tid;
            u64 got = 0;
            bool found = false;
            if (!mdead) {
                // fast path: L1-invalidate + plain coalesced load -> L2.
                for (int rot = 0; rot < NROT; ++rot) {
                    u64 v;
                    asm volatile("buffer_inv sc0\n\t"
                                 "global_load_dwordx2 %0, %1, off\n\t"
                                 "s_waitcnt vmcnt(0)"
                                 : "=v"(v) : "v"(mslot) : "memory");
                    if ((u32)(v >> 32) == want) { got = v; found = true; break; }
                }
                if (found) miss_streak = 0;
                else if (++miss_streak >= 3) mdead = true;
            }
            if (!found) {
                // canonical agent-scope 3-deep rotation (baseline-proven;
                // correct under ANY placement).
                u64 v0, v1, v2;
                asm volatile("global_load_dwordx2 %0, %3, off sc0 sc1\n\t"
                             "global_load_dwordx2 %1, %3, off sc0 sc1\n\t"
                             "global_load_dwordx2 %2, %3, off sc0 sc1"
                             : "=&v"(v0), "=&v"(v1), "=&v"(v2)
                             : "v"(cslot) : "memory");
                while (true) {
                    asm volatile("s_waitcnt vmcnt(2)" : "+v"(v0) :: "memory");
                    __builtin_amdgcn_sched_barrier(0);
                    if ((u32)(v0 >> 32) == want) { got = v0; break; }
                    asm volatile("global_load_dwordx2 %0, %1, off sc0 sc1"
                                 : "=&v"(v0) : "v"(cslot) : "memory");
                    asm volatile("s_waitcnt vmcnt(2)" : "+v"(v1) :: "memory");
                    __builtin_amdgcn_sched_barrier(0);
                    if ((u32)(v1 >> 32) == want) { got = v1; break; }
                    asm volatile("global_load_dwordx2 %0, %1, off sc0 sc1"
                                 : "=&v"(v1) : "v"(cslot) : "memory");
                    asm volatile("s_waitcnt vmcnt(2)" : "+v"(v2) :: "memory");
                    __builtin_amdgcn_sched_barrier(0);
                    if ((u32)(v2 >> 32) == want) { got = v2; break; }
                    asm volatile("global_load_dwordx2 %0, %1, off sc0 sc1"
                                 : "=&v"(v2) : "v"(cslot) : "memory");
                }
                // drain the two still-in-flight rotation loads so later
                // hand-counted waits stay honest.
                asm volatile("s_waitcnt vmcnt(0)" ::: "memory");
            }
            hval = __uint_as_float((u32)got);
        }

        // xw load AFTER the poll (keeps hand-counted vmcnt honest);
        // overlaps the dot below, consumed in the funnel.
        float xwv = 0.f;
        if (tid < 64)
            xwv = xw[((size_t)(dir * L) + t) * G4H + wg * 64 + l];

        // ---- dot: row l over slice wv via readlane broadcast, 4 accs ----
        float a0 = 0.f, a1 = 0.f, a2 = 0.f, a3 = 0.f;
#pragma unroll
        for (int i = 0; i < 64; i += 4) {
            float h0v = __uint_as_float((u32)__builtin_amdgcn_readlane(
                            (int)__float_as_uint(hval), i));
            float h1v = __uint_as_float((u32)__builtin_amdgcn_readlane(
                            (int)__float_as_uint(hval), i + 1));
            float h2v = __uint_as_float((u32)__builtin_amdgcn_readlane(
                            (int)__float_as_uint(hval), i + 2));
            float h3v = __uint_as_float((u32)__builtin_amdgcn_readlane(
                            (int)__float_as_uint(hval), i + 3));
            a0 = fmaf(w[i],     h0v, a0);
            a1 = fmaf(w[i + 1], h1v, a1);
            a2 = fmaf(w[i + 2], h2v, a2);
            a3 = fmaf(w[i + 3], h3v, a3);
        }
        PB(par, wv, l) = (a0 + a1) + (a2 + a3);
        __syncthreads();

        // ---- wave0 funnel tail: reduce 8 partials, gates, publish ----
        if (tid < 64) {
            float tot = 0.f;
#pragma unroll
            for (int p = 0; p < 8; ++p) tot += PB(par, p, l);
            float pre = tot + xwv;
            float aa = (g == 2) ? 2.f * pre : pre;       // tanh = 2*sig(2x)-1
            float sg = 1.f / (1.f + __expf(-aa));
            float vg = (g == 2) ? (2.f * sg - 1.f) : sg;
            float gi = __shfl(vg, j);
            float gf = __shfl(vg, 16 + j);
            float gg = __shfl(vg, 32 + j);
            float go = __shfl(vg, 48 + j);
            if (tid < 16) {
                c = gf * c + gi * gg;
                float th = 2.f / (1.f + __expf(-2.f * c)) - 1.f;
                float hout = go * th;
                u64 e = ((u64)(u32)s << 32) | (u64)__float_as_uint(hout);
                const u64* ma = mird + par * 512 + wg * 16 + tid;
                const u64* ca = hb + par * 512 + wg * 16 + tid;
                // mirror: plain write-through store -> producer's XCD L2
                asm volatile("global_store_dwordx2 %0, %1, off"
                             :: "v"(ma), "v"(e) : "memory");
                // canonical: through the coherence point, any placement
                asm volatile("global_store_dwordx2 %0, %1, off sc0 sc1"
                             :: "v"(ca), "v"(e) : "memory");
                histd[(size_t)t * H + wg * 16 + tid] = hout;
            }
        }
        // pbuf parity double-buffer + the single barrier covers reuse
    }
#undef PB
}

// ---------------------------------------------------------------------------
// K3: feats[t][tag] = b_out[tag] + concat(hf,hb)[t] . w_out[tag]   (f32)
__global__ void k3_feats(const float* __restrict__ hist,
                         const float* __restrict__ wout,
                         const float* __restrict__ bout,
                         float* __restrict__ feats) {
    int t = blockIdx.x;
    int tid = threadIdx.x;
    int tag = tid >> 4;       // [0,20)
    int part = tid & 15;
    const float* h0p = hist + (size_t)t * H;
    const float* h1p = hist + (size_t)L * H + (size_t)t * H;
    int j0 = part * 64;
    float acc = 0.f;
    for (int jj = 0; jj < 64; jj += 4) {
        int j = j0 + jj;
        float4 w4 = *(const float4*)(wout + (size_t)tag * (2 * H) + j);
        float4 h4 = (j < H) ? *(const float4*)(h0p + j)
                            : *(const float4*)(h1p + (j - H));
        acc = fmaf(w4.x, h4.x, fmaf(w4.y, h4.y,
              fmaf(w4.z, h4.z, fmaf(w4.w, h4.w, acc))));
    }
    acc += __shfl_xor(acc, 8, 16);
    acc += __shfl_xor(acc, 4, 16);
    acc += __shfl_xor(acc, 2, 16);
    acc += __shfl_xor(acc, 1, 16);
    if (part == 0) feats[(size_t)t * NTAGS + tag] = acc + bout[tag];
}

// ---------------------------------------------------------------------------
// K4: Viterbi + backtrack, one wave. Batched shfls + index-carrying tree-max
// (exact first-max semantics).
__global__ void k4_viterbi(const float* __restrict__ feats,
                           const float* __restrict__ trans,
                           int* __restrict__ out) {
    __shared__ unsigned char bp[L * NTAGS];
    int lane = threadIdx.x;           // 64 threads
    bool act = lane < NTAGS;

    float trl[NTAGS];
#pragma unroll
    for (int p = 0; p < NTAGS; ++p)
        trl[p] = act ? trans[lane * NTAGS + p] : -1.0e30f;

    float fv = (lane == START_TAG) ? 0.f : -10000.f;
    float nf = act ? feats[lane] : 0.f;

    for (int t = 0; t < L; ++t) {
        float f = nf;
        if (act && t + 1 < L) nf = feats[(size_t)(t + 1) * NTAGS + lane];
        float tv[NTAGS];
        int   ti[NTAGS];
#pragma unroll
        for (int p = 0; p < NTAGS; ++p) {
            tv[p] = __shfl(fv, p) + trl[p];
            ti[p] = p;
        }
#pragma unroll
        for (int p = 0; p < 4; ++p) {
            bool take = (tv[p + 16] > tv[p]) ||
                        (tv[p + 16] == tv[p] && ti[p + 16] < ti[p]);
            if (take) { tv[p] = tv[p + 16]; ti[p] = ti[p + 16]; }
        }
#pragma unroll
        for (int w = 8; w >= 1; w >>= 1)
#pragma unroll
            for (int p = 0; p < 16; ++p) if (p < w) {
                bool take = (tv[p + w] > tv[p]) ||
                            (tv[p + w] == tv[p] && ti[p + w] < ti[p]);
                if (take) { tv[p] = tv[p + w]; ti[p] = ti[p + w]; }
            }
        fv = tv[0] + f;
        if (act) bp[t * NTAGS + lane] = (unsigned char)ti[0];
    }

    float ts = act ? fv + trans[STOP_TAG * NTAGS + lane] : -1.0e30f;
    int bi = lane;
#pragma unroll
    for (int off = 32; off; off >>= 1) {
        float ov = __shfl_down(ts, off);
        int   oi = __shfl_down(bi, off);
        if (ov > ts) { ts = ov; bi = oi; }
    }
    if (lane == 0) {
        int tag = bi;
        out[L - 1] = tag;
        for (int t = L - 1; t >= 1; --t) {
            tag = bp[t * NTAGS + tag];
            out[t - 1] = tag;
        }
    }
}

// ---------------------------------------------------------------------------
extern "C" void kernel_launch(void* const* d_in, const int* in_sizes, int n_in,
                              void* d_out, int out_size, void* d_ws, size_t ws_size,
                              hipStream_t stream) {
    const int*   sentence = (const int*)d_in[0];
    const float* embed    = (const float*)d_in[1];
    const float* wih_f    = (const float*)d_in[2];
    const float* whh_f    = (const float*)d_in[3];
    const float* bih_f    = (const float*)d_in[4];
    const float* bhh_f    = (const float*)d_in[5];
    const float* wih_b    = (const float*)d_in[6];
    const float* whh_b    = (const float*)d_in[7];
    const float* bih_b    = (const float*)d_in[8];
    const float* bhh_b    = (const float*)d_in[9];
    const float* h0       = (const float*)d_in[10];
    const float* c0       = (const float*)d_in[11];
    const float* wout     = (const float*)d_in[12];
    const float* bout     = (const float*)d_in[13];
    const float* trans    = (const float*)d_in[14];
    int* out = (int*)d_out;

    char* ws = (char*)d_ws;
    float* xw    = (float*)(ws + OFF_XW);
    float* hist  = (float*)(ws + OFF_HIST);
    float* feats = (float*)(ws + OFF_FEATS);
    u64*   hbuf  = (u64*)(ws + OFF_HBUF);
    u64*   mir   = (u64*)(ws + OFF_FEATS);            // dead until k3

    k0_init<<<1, 256, 0, stream>>>(mir);
    k1_xw<<<dim3(32, 8, 2), 256, 0, stream>>>(sentence, embed, wih_f, wih_b,
                                              bih_f, bhh_f, bih_b, bhh_b, xw);
    k2_lstm<<<256, 512, 0, stream>>>(whh_f, whh_b, h0, c0, xw, hist, hbuf, mir);
    k3_feats<<<L, 320, 0, stream>>>(hist, wout, bout, feats);
    k4_viterbi<<<1, 64, 0, stream>>>(feats, trans, out);
}

// Round 7
// 1465.954 us; speedup vs baseline: 1.3683x; 1.0796x over previous
//
#include <hip/hip_runtime.h>
#include <math.h>

typedef unsigned long long u64;
typedef unsigned int u32;

// Problem constants
#define L 512
#define E 300
#define H 512          // per-direction hidden
#define G4H 2048       // 4*H
#define NTAGS 20
#define START_TAG 18
#define STOP_TAG 19

#define KC 100         // k1 K-chunk (300 = 3*100)

// Workspace layout (bytes)
#define OFF_XW    0u          // f32 [2][512][2048] (permuted cols) = 8388608
#define OFF_HIST  8388608u    // f32 [2][512][512]  = 2097152
#define OFF_HBUF  10485760u   // u64 [2][2][512]    = 16384
#define OFF_FEATS 10502144u   // f32 [512][20]      = 40960

// ---------------------------------------------------------------------------
// K1: tiled GEMM  xw[dir][t][pos(n)] = embed[sent[t]] . wih[n] + bias(n).
// (unchanged from verified baseline)
__global__ __launch_bounds__(256) void k1_xw(
    const int* __restrict__ sentence, const float* __restrict__ embed,
    const float* __restrict__ wih_f, const float* __restrict__ wih_b,
    const float* __restrict__ bih_f, const float* __restrict__ bhh_f,
    const float* __restrict__ bih_b, const float* __restrict__ bhh_b,
    float* __restrict__ xw) {
    __shared__ float wST[KC][68];   // [k][n]
    __shared__ float xST[KC][68];   // [k][t]
    __shared__ int   sT[64];

    const int tid = threadIdx.x;
    const int tx = tid & 15;        // t micro index
    const int ty = tid >> 4;        // n micro index
    const int n_base = blockIdx.x * 64;
    const int t_base = blockIdx.y * 64;
    const int dir = blockIdx.z;
    const float* wih = dir ? wih_b : wih_f;
    const float* bih = dir ? bih_b : bih_f;
    const float* bhh = dir ? bhh_b : bhh_f;

    if (tid < 64) sT[tid] = sentence[t_base + tid];
    __syncthreads();

    float acc[4][4];
#pragma unroll
    for (int i = 0; i < 4; ++i)
#pragma unroll
        for (int j = 0; j < 4; ++j) acc[i][j] = 0.f;

    for (int kc = 0; kc < E; kc += KC) {
#pragma unroll
        for (int i = 0; i < 25; ++i) {
            int idx = i * 256 + tid;          // < 6400
            int row = idx / KC, col = idx % KC;
            wST[col][row] = wih[(size_t)(n_base + row) * E + kc + col];
        }
#pragma unroll
        for (int i = 0; i < 25; ++i) {
            int idx = i * 256 + tid;
            int trow = idx / KC, col = idx % KC;
            xST[col][trow] = embed[(size_t)sT[trow] * E + kc + col];
        }
        __syncthreads();

#pragma unroll 4
        for (int k = 0; k < KC; ++k) {
            float4 wv4 = *(const float4*)&wST[k][ty * 4];
            float4 xv4 = *(const float4*)&xST[k][tx * 4];
            float wv[4] = {wv4.x, wv4.y, wv4.z, wv4.w};
            float xv[4] = {xv4.x, xv4.y, xv4.z, xv4.w};
#pragma unroll
            for (int i = 0; i < 4; ++i)
#pragma unroll
                for (int j = 0; j < 4; ++j)
                    acc[i][j] = fmaf(wv[i], xv[j], acc[i][j]);
        }
        __syncthreads();
    }

#pragma unroll
    for (int i = 0; i < 4; ++i) {
        int n = n_base + ty * 4 + i;
        float b = bih[n] + bhh[n];
        int u = n & (H - 1), g = n >> 9;
        int pos = (u >> 4) * 64 + g * 16 + (u & 15);   // gate-major in block
#pragma unroll
        for (int j = 0; j < 4; ++j) {
            int t = t_base + tx * 4 + j;
            xw[((size_t)(dir * L) + t) * G4H + pos] = acc[i][j] + b;
        }
    }
}

// ---------------------------------------------------------------------------
// K2: bidirectional LSTM recurrence. REVERTED to the r0-proven agent-scope
// protocol (854us) after the XCD-clustering arc (r2-r6) failed: every
// cross-L2 mirror transport was either stale (sc0 served by consumer's own
// vL1D / dirty lines invisible at the MALL) or slow (per-sample buffer_inv
// serialization, system-scope flags, divergent fallbacks). All five
// variants benched >= baseline, so the agent path IS the transport.
//
// Two safe deltas vs r0:
//  - poll rotation deepened 3 -> 4 (sampling ~RT/4 vs RT/3)
//  - s_setprio(1) around the wave0 funnel tail: genuine role diversity
//    (wave0 computes gates while waves 1-7 issue next-step poll loads),
//    the measured prerequisite for setprio to pay.
__global__ __launch_bounds__(512) void k2_lstm(
    const float* __restrict__ whh_f, const float* __restrict__ whh_b,
    const float* __restrict__ h0, const float* __restrict__ c0,
    const float* __restrict__ xw, float* __restrict__ hist,
    u64* __restrict__ hbuf) {
    const int bid = blockIdx.x;
    const int dir = bid >> 5;
    const int wg  = bid & 31;
    const int tid = threadIdx.x;
    const int wv  = tid >> 6;       // wave id = dot k-slice
    const int l   = tid & 63;
    const int g   = l >> 4;         // gate: 0=i 1=f 2=g 3=o
    const int j   = l & 15;         // unit within WG
    const int grow = g * H + wg * 16 + j;

    const float* whh = dir ? whh_b : whh_f;
    float* histd = hist + (size_t)dir * L * H;
    u64* hb = hbuf + dir * 1024;    // [parity][512]

    // this lane's 64 Whh weights (row grow, slice wv) -> regs
    float w[64];
    {
        const float* wp = whh + (size_t)grow * H + wv * 64;
#pragma unroll
        for (int i = 0; i < 64; i += 4) {
            float4 v = *(const float4*)(wp + i);
            w[i] = v.x; w[i+1] = v.y; w[i+2] = v.z; w[i+3] = v.w;
        }
    }

    __shared__ float pbuf[2][8][68];   // [parity][slice][row(+pad)]

    // c state lives on wave0 lanes 0..15 (unit = wg*16 + tid)
    float c = (tid < 16) ? c0[dir * H + wg * 16 + tid] : 0.f;

    for (int s = 1; s <= L; ++s) {
        const int t = dir ? (L - s) : (s - 1);
        const int par = s & 1;

        // xw for wave0's tail rows: coalesced 64-lane load (gate-major layout)
        float xwv = 0.f;
        if (tid < 64)
            xwv = xw[((size_t)(dir * L) + t) * G4H + wg * 64 + l];

        // ---- acquire h_{s-1}[tid]: 4-deep pipelined poll on own slot ----
        float hval;
        if (s == 1) {
            hval = h0[dir * H + tid];
        } else {
            const u32 want = (u32)(s - 1);
            u64* slot = hb + ((s - 1) & 1) * 512 + tid;
            u64 v0 = __hip_atomic_load(slot, __ATOMIC_RELAXED, __HIP_MEMORY_SCOPE_AGENT);
            u64 v1 = __hip_atomic_load(slot, __ATOMIC_RELAXED, __HIP_MEMORY_SCOPE_AGENT);
            u64 v2 = __hip_atomic_load(slot, __ATOMIC_RELAXED, __HIP_MEMORY_SCOPE_AGENT);
            u64 v3 = __hip_atomic_load(slot, __ATOMIC_RELAXED, __HIP_MEMORY_SCOPE_AGENT);
            while ((u32)(v0 >> 32) != want) {
                v0 = v1; v1 = v2; v2 = v3;
                v3 = __hip_atomic_load(slot, __ATOMIC_RELAXED, __HIP_MEMORY_SCOPE_AGENT);
            }
            hval = __uint_as_float((u32)v0);
        }

        // ---- dot: row l over slice wv via readlane broadcast, 4 accs ----
        float a0 = 0.f, a1 = 0.f, a2 = 0.f, a3 = 0.f;
#pragma unroll
        for (int i = 0; i < 64; i += 4) {
            float h0v = __uint_as_float((u32)__builtin_amdgcn_readlane(
                            (int)__float_as_uint(hval), i));
            float h1v = __uint_as_float((u32)__builtin_amdgcn_readlane(
                            (int)__float_as_uint(hval), i + 1));
            float h2v = __uint_as_float((u32)__builtin_amdgcn_readlane(
                            (int)__float_as_uint(hval), i + 2));
            float h3v = __uint_as_float((u32)__builtin_amdgcn_readlane(
                            (int)__float_as_uint(hval), i + 3));
            a0 = fmaf(w[i],     h0v, a0);
            a1 = fmaf(w[i + 1], h1v, a1);
            a2 = fmaf(w[i + 2], h2v, a2);
            a3 = fmaf(w[i + 3], h3v, a3);
        }
        pbuf[par][wv][l] = (a0 + a1) + (a2 + a3);
        __syncthreads();

        // ---- wave0 funnel tail: reduce 8 partials, gates, publish ----
        if (tid < 64) {
            __builtin_amdgcn_s_setprio(1);   // favor the funnel wave while
                                             // waves 1-7 poll for step s+1
            float tot = 0.f;
#pragma unroll
            for (int p = 0; p < 8; ++p) tot += pbuf[par][p][l];
            float pre = tot + xwv;
            float aa = (g == 2) ? 2.f * pre : pre;       // tanh = 2*sig(2x)-1
            float sg = 1.f / (1.f + __expf(-aa));
            float vg = (g == 2) ? (2.f * sg - 1.f) : sg;
            float gi = __shfl(vg, j);
            float gf = __shfl(vg, 16 + j);
            float gg = __shfl(vg, 32 + j);
            float go = __shfl(vg, 48 + j);
            if (tid < 16) {
                c = gf * c + gi * gg;
                float th = 2.f / (1.f + __expf(-2.f * c)) - 1.f;
                float hout = go * th;
                // single coalesced 128B publish (16 lanes x 8B, contiguous)
                u64 e = ((u64)(u32)s << 32) | (u64)__float_as_uint(hout);
                __hip_atomic_store(hb + par * 512 + wg * 16 + tid, e,
                                   __ATOMIC_RELAXED, __HIP_MEMORY_SCOPE_AGENT);
                histd[(size_t)t * H + wg * 16 + tid] = hout;
            }
            __builtin_amdgcn_s_setprio(0);
        }
        // pbuf parity double-buffer + the single barrier covers reuse
    }
}

// ---------------------------------------------------------------------------
// K3: feats[t][tag] = b_out[tag] + concat(hf,hb)[t] . w_out[tag]   (f32)
__global__ void k3_feats(const float* __restrict__ hist,
                         const float* __restrict__ wout,
                         const float* __restrict__ bout,
                         float* __restrict__ feats) {
    int t = blockIdx.x;
    int tid = threadIdx.x;
    int tag = tid >> 4;       // [0,20)
    int part = tid & 15;
    const float* h0p = hist + (size_t)t * H;
    const float* h1p = hist + (size_t)L * H + (size_t)t * H;
    int j0 = part * 64;
    float acc = 0.f;
    for (int jj = 0; jj < 64; jj += 4) {
        int j = j0 + jj;
        float4 w4 = *(const float4*)(wout + (size_t)tag * (2 * H) + j);
        float4 h4 = (j < H) ? *(const float4*)(h0p + j)
                            : *(const float4*)(h1p + (j - H));
        acc = fmaf(w4.x, h4.x, fmaf(w4.y, h4.y,
              fmaf(w4.z, h4.z, fmaf(w4.w, h4.w, acc))));
    }
    acc += __shfl_xor(acc, 8, 16);
    acc += __shfl_xor(acc, 4, 16);
    acc += __shfl_xor(acc, 2, 16);
    acc += __shfl_xor(acc, 1, 16);
    if (part == 0) feats[(size_t)t * NTAGS + tag] = acc + bout[tag];
}

// ---------------------------------------------------------------------------
// K4: Viterbi + backtrack, one wave. Batched shfls + index-carrying tree-max
// (exact first-max semantics).
__global__ void k4_viterbi(const float* __restrict__ feats,
                           const float* __restrict__ trans,
                           int* __restrict__ out) {
    __shared__ unsigned char bp[L * NTAGS];
    int lane = threadIdx.x;           // 64 threads
    bool act = lane < NTAGS;

    float trl[NTAGS];
#pragma unroll
    for (int p = 0; p < NTAGS; ++p)
        trl[p] = act ? trans[lane * NTAGS + p] : -1.0e30f;

    float fv = (lane == START_TAG) ? 0.f : -10000.f;
    float nf = act ? feats[lane] : 0.f;

    for (int t = 0; t < L; ++t) {
        float f = nf;
        if (act && t + 1 < L) nf = feats[(size_t)(t + 1) * NTAGS + lane];
        float tv[NTAGS];
        int   ti[NTAGS];
#pragma unroll
        for (int p = 0; p < NTAGS; ++p) {
            tv[p] = __shfl(fv, p) + trl[p];
            ti[p] = p;
        }
#pragma unroll
        for (int p = 0; p < 4; ++p) {
            bool take = (tv[p + 16] > tv[p]) ||
                        (tv[p + 16] == tv[p] && ti[p + 16] < ti[p]);
            if (take) { tv[p] = tv[p + 16]; ti[p] = ti[p + 16]; }
        }
#pragma unroll
        for (int w = 8; w >= 1; w >>= 1)
#pragma unroll
            for (int p = 0; p < 16; ++p) if (p < w) {
                bool take = (tv[p + w] > tv[p]) ||
                            (tv[p + w] == tv[p] && ti[p + w] < ti[p]);
                if (take) { tv[p] = tv[p + w]; ti[p] = ti[p + w]; }
            }
        fv = tv[0] + f;
        if (act) bp[t * NTAGS + lane] = (unsigned char)ti[0];
    }

    float ts = act ? fv + trans[STOP_TAG * NTAGS + lane] : -1.0e30f;
    int bi = lane;
#pragma unroll
    for (int off = 32; off; off >>= 1) {
        float ov = __shfl_down(ts, off);
        int   oi = __shfl_down(bi, off);
        if (ov > ts) { ts = ov; bi = oi; }
    }
    if (lane == 0) {
        int tag = bi;
        out[L - 1] = tag;
        for (int t = L - 1; t >= 1; --t) {
            tag = bp[t * NTAGS + tag];
            out[t - 1] = tag;
        }
    }
}

// ---------------------------------------------------------------------------
extern "C" void kernel_launch(void* const* d_in, const int* in_sizes, int n_in,
                              void* d_out, int out_size, void* d_ws, size_t ws_size,
                              hipStream_t stream) {
    const int*   sentence = (const int*)d_in[0];
    const float* embed    = (const float*)d_in[1];
    const float* wih_f    = (const float*)d_in[2];
    const float* whh_f    = (const float*)d_in[3];
    const float* bih_f    = (const float*)d_in[4];
    const float* bhh_f    = (const float*)d_in[5];
    const float* wih_b    = (const float*)d_in[6];
    const float* whh_b    = (const float*)d_in[7];
    const float* bih_b    = (const float*)d_in[8];
    const float* bhh_b    = (const float*)d_in[9];
    const float* h0       = (const float*)d_in[10];
    const float* c0       = (const float*)d_in[11];
    const float* wout     = (const float*)d_in[12];
    const float* bout     = (const float*)d_in[13];
    const float* trans    = (const float*)d_in[14];
    int* out = (int*)d_out;

    char* ws = (char*)d_ws;
    float* xw    = (float*)(ws + OFF_XW);
    float* hist  = (float*)(ws + OFF_HIST);
    float* feats = (float*)(ws + OFF_FEATS);
    u64*   hbuf  = (u64*)(ws + OFF_HBUF);

    k1_xw<<<dim3(32, 8, 2), 256, 0, stream>>>(sentence, embed, wih_f, wih_b,
                                              bih_f, bhh_f, bih_b, bhh_b, xw);
    k2_lstm<<<64, 512, 0, stream>>>(whh_f, whh_b, h0, c0, xw, hist, hbuf);
    k3_feats<<<L, 320, 0, stream>>>(hist, wout, bout, feats);
    k4_viterbi<<<1, 64, 0, stream>>>(feats, trans, out);
}